// Round 7
// baseline (487.507 us; speedup 1.0000x reference)
//
#include <hip/hip_runtime.h>
#include <hip/hip_bf16.h>
#include <stdint.h>

// Problem-fixed shapes
#define B_ 8
#define S_ 2048
#define F_ 2048
#define M_ (B_*S_)   // 16384 rows (b*S+s)
#define K_ F_
#define N_ F_

typedef __attribute__((ext_vector_type(4))) float f32x4;
typedef __attribute__((ext_vector_type(8))) short short8;

// ---------- helpers ----------
__device__ __forceinline__ unsigned short f2bf(float f){
  unsigned u = __float_as_uint(f);
  u += 0x7FFFu + ((u >> 16) & 1u);   // round-to-nearest-even
  return (unsigned short)(u >> 16);
}

__device__ __forceinline__ void gload16(const void* g, const void* l){
  __builtin_amdgcn_global_load_lds(
      (const __attribute__((address_space(1))) void*)g,
      (__attribute__((address_space(3))) void*)l,
      16, 0, 0);
}

__device__ __forceinline__ float waveReduce(float v){
  #pragma unroll
  for (int off = 32; off; off >>= 1) v += __shfl_down(v, off, 64);
  return v;
}

__device__ __forceinline__ float blockReduceAll(float v, float* sbuf){
  v = waveReduce(v);
  int lane = threadIdx.x & 63, w = threadIdx.x >> 6;
  __syncthreads();
  if (lane == 0) sbuf[w] = v;
  __syncthreads();
  return sbuf[0] + sbuf[1] + sbuf[2] + sbuf[3];
}

// ---------- 1) sum(|W|) -> scalep[0] (consumers divide by F*F) ----------
__global__ __launch_bounds__(256) void k_abs1(const float* __restrict__ W, float* __restrict__ scalep){
  __shared__ float sb[4];
  size_t idx = ((size_t)blockIdx.x * 256 + threadIdx.x) * 4;
  f32x4 v = *(const f32x4*)(W + idx);
  float s = fabsf(v[0]) + fabsf(v[1]) + fabsf(v[2]) + fabsf(v[3]);
  s = blockReduceAll(s, sb);
  if (threadIdx.x == 0) atomicAdd(scalep, s);
}

// ---------- 2) quantize W -> ternary bf16, transposed: BT[g][f] ----------
__global__ __launch_bounds__(256) void k_quantT(const float* __restrict__ W, unsigned short* __restrict__ BT,
                                                const float* __restrict__ scalep){
  __shared__ float tile[32][33];
  int gx = blockIdx.x * 32;
  int fy = blockIdx.y * 32;
  int tx = threadIdx.x & 31, ty = threadIdx.x >> 5;
  float scale = scalep[0] * (1.0f / ((float)F_ * (float)F_));
  float inv = 1.0f / (scale + 1e-8f);
  #pragma unroll
  for (int i = 0; i < 4; i++){
    int f = fy + ty + i*8;
    tile[ty + i*8][tx] = W[(size_t)f * F_ + gx + tx];
  }
  __syncthreads();
  #pragma unroll
  for (int i = 0; i < 4; i++){
    int g = gx + ty + i*8;
    float w = tile[tx][ty + i*8];
    float t = rintf(w * inv);
    t = fminf(1.0f, fmaxf(-1.0f, t));
    BT[(size_t)g * K_ + fy + tx] = f2bf(t);
  }
}

// ---------- 3) fused front-end: one pass over X ----------
// Block covers 32 rows. Batched end-of-loop reduction (32 independent shfl trees).
__global__ __launch_bounds__(256) void k_front(const float* __restrict__ X, const float* __restrict__ wl,
                                               const float* __restrict__ bl, const float* __restrict__ wrt,
                                               unsigned short* __restrict__ XH, float* __restrict__ la_raw,
                                               float* __restrict__ ra_raw){
  __shared__ float lap[4][32];
  int t = threadIdx.x, w = t >> 6, lane = t & 63;
  int r0 = blockIdx.x * 32;
  int b  = r0 >> 11;                 // r0 / S_
  int f0 = t * 8;
  f32x4 wl0 = *(const f32x4*)(wl + f0);
  f32x4 wl1 = *(const f32x4*)(wl + f0 + 4);
  float dots[32];
  float racc[8];
  #pragma unroll
  for (int j = 0; j < 8; j++) racc[j] = 0.f;

  #pragma unroll
  for (int rr = 0; rr < 32; ++rr){
    int row = r0 + rr;
    const float* xr = X + (size_t)row * F_ + f0;
    f32x4 v0 = *(const f32x4*)(xr);
    f32x4 v1 = *(const f32x4*)(xr + 4);
    ushort4 p0, p1;
    p0.x = f2bf(v0[0]); p0.y = f2bf(v0[1]); p0.z = f2bf(v0[2]); p0.w = f2bf(v0[3]);
    p1.x = f2bf(v1[0]); p1.y = f2bf(v1[1]); p1.z = f2bf(v1[2]); p1.w = f2bf(v1[3]);
    unsigned short* xh = XH + (size_t)row * F_ + f0;
    *(ushort4*)(xh)     = p0;
    *(ushort4*)(xh + 4) = p1;
    dots[rr] = v0[0]*wl0[0] + v0[1]*wl0[1] + v0[2]*wl0[2] + v0[3]*wl0[3]
             + v1[0]*wl1[0] + v1[1]*wl1[1] + v1[2]*wl1[2] + v1[3]*wl1[3];
    float wsr = wrt[row & (S_-1)];
    racc[0] += v0[0]*wsr; racc[1] += v0[1]*wsr; racc[2] += v0[2]*wsr; racc[3] += v0[3]*wsr;
    racc[4] += v1[0]*wsr; racc[5] += v1[1]*wsr; racc[6] += v1[2]*wsr; racc[7] += v1[3]*wsr;
  }
  // batched 64-lane tree reduce: 32 independent chains -> throughput-bound
  #pragma unroll
  for (int off = 32; off; off >>= 1){
    #pragma unroll
    for (int rr = 0; rr < 32; ++rr) dots[rr] += __shfl_down(dots[rr], off, 64);
  }
  if (lane == 0){
    #pragma unroll
    for (int rr = 0; rr < 32; ++rr) lap[w][rr] = dots[rr];
  }
  __syncthreads();
  if (t < 32)
    la_raw[r0 + t] = lap[0][t] + lap[1][t] + lap[2][t] + lap[3][t] + bl[0];
  float* rb = ra_raw + b * F_ + f0;
  #pragma unroll
  for (int j = 0; j < 8; j++) atomicAdd(&rb[j], racc[j]);
}

// ---------- 4) merged LN: blocks 0..7 = la over S; blocks 8..15 = ra over F ----------
__global__ __launch_bounds__(256) void k_ln(const float* __restrict__ la_raw, const float* __restrict__ ra_raw,
                                            const float* __restrict__ br, float* __restrict__ la,
                                            float* __restrict__ ra){
  __shared__ float sb[4];
  int blk = blockIdx.x;
  bool isRa = blk >= 8;
  int b = blk & 7;
  const float* p = isRa ? (ra_raw + b * F_) : (la_raw + b * S_);
  int t = threadIdx.x;
  float bb = isRa ? br[0] : 0.0f;
  float v[8]; float s = 0.f, s2 = 0.f;
  #pragma unroll
  for (int i = 0; i < 8; i++){ v[i] = p[t + i*256] + bb; s += v[i]; s2 += v[i]*v[i]; }
  s  = blockReduceAll(s,  sb);
  s2 = blockReduceAll(s2, sb);
  float mu  = s * (1.0f / 2048.0f);
  float var = s2 * (1.0f / 2048.0f) - mu*mu;
  float rstd = 1.0f / sqrtf(var + 1e-5f);
  float r[8]; float sr = 0.f;
  #pragma unroll
  for (int i = 0; i < 8; i++){ r[i] = fmaxf((v[i] - mu) * rstd, 0.0f); sr += r[i]; }
  if (isRa){
    sr = blockReduceAll(sr, sb);
    float invs = 1.0f / (sr + 1e-6f);
    #pragma unroll
    for (int i = 0; i < 8; i++) ra[b * F_ + t + i*256] = r[i] * invs;
  } else {
    #pragma unroll
    for (int i = 0; i < 8; i++) la[b * S_ + t + i*256] = r[i] / (r[i] + 1e-6f);
  }
}

// ---------- 5) GEMM: 256x256 tile, 512 threads (2x4 waves), BK=32, depth-3 ----------
// A = XH [M][K] bf16; B^T = BT [N][K] bf16. Wave tile 128x64: 8 A-frags, 4 B-frags,
// 32 MFMA per K-step (4x the MFMA per ds_read of the 128^2 version).
// 4 LDS buffers x 32KB (A[256][32] 16KB | B[256][32] 16KB) = 128KB.
// Counted vmcnt: at iter kt stage kt+3 (4 loads/thread), wait vmcnt(8) -> tile
// kt+1 landed; raw s_barrier. Buffer staged at kt was last ds_read at kt-1 and
// those reads are register-consumed (lgkmcnt) before kt-1's barrier -> no race.
// Swizzle (both-sides): 16B-quad p of row r holds global quad p ^ ((r>>1)&3);
// identical formula on stage-source and ds_read side (verified: 0 conflicts).
__global__ __launch_bounds__(512, 2) void k_gemm(
    const unsigned short* __restrict__ A, const unsigned short* __restrict__ BT,
    const float* __restrict__ X, const float* __restrict__ la, const float* __restrict__ ra,
    const float* __restrict__ bv, const float* __restrict__ alphap, const float* __restrict__ scalep,
    float* __restrict__ Out)
{
  __shared__ __align__(128) char lds[131072];
  const int NBX = N_ / 256;                    // 8
  const int NT  = K_ / 32;                     // 64
  int tid = threadIdx.x;
  int bid = blockIdx.x;
  const int nwg = (M_/256) * (N_/256);         // 512, divisible by 8
  int cpx = nwg >> 3;
  int swz = (bid & 7) * cpx + (bid >> 3);
  int brow = swz / NBX, bcol = swz % NBX;
  int row0 = brow * 256, col0 = bcol * 256;

  int w = tid >> 6, lane = tid & 63;
  int wr = w >> 2, wc = w & 3;                 // 2x4 waves, each 128x64
  int lrow = lane & 15, kgrp = lane >> 4;

  f32x4 acc[8][4];
  #pragma unroll
  for (int m = 0; m < 8; m++)
    #pragma unroll
    for (int n = 0; n < 4; n++) acc[m][n] = (f32x4)(0.0f);

  // staging: per buffer A[256][32] at [0,16K), B[256][32] at [16K,32K).
  // thread handles chunks {tid, tid+512, tid+1024, tid+1536}; chunk c at byte c*16.
  int ar0 = tid >> 2;                                   // 0..127
  int q0  = ((tid & 3) ^ ((ar0 >> 1) & 3)) << 3;        // elem offset of swizzled quad
  // note: ((ar0+128)>>1)&3 == (ar0>>1)&3, so same q0 for the +128 rows
  const unsigned short* Ap0 = A  + (size_t)(row0 + ar0      ) * K_ + q0;
  const unsigned short* Ap1 = A  + (size_t)(row0 + ar0 + 128) * K_ + q0;
  const unsigned short* Bp0 = BT + (size_t)(col0 + ar0      ) * K_ + q0;
  const unsigned short* Bp1 = BT + (size_t)(col0 + ar0 + 128) * K_ + q0;
  int stoff = w * 1024;                        // + lane*16 implicit

  // ds_read offsets (swizzled)
  int aoff[8], boff[4];
  #pragma unroll
  for (int m = 0; m < 8; m++){
    int r  = wr*128 + m*16 + lrow;
    aoff[m] = r*64 + ((kgrp ^ ((r >> 1) & 3)) << 4);
  }
  #pragma unroll
  for (int n = 0; n < 4; n++){
    int rc = wc*64 + n*16 + lrow;
    boff[n] = 16384 + rc*64 + ((kgrp ^ ((rc >> 1) & 3)) << 4);
  }

#define STAGE(T) { \
    char* nb_ = lds + ((T) & 3) * 32768; \
    gload16(Ap0 + (size_t)(T)*32, nb_ + stoff); \
    gload16(Ap1 + (size_t)(T)*32, nb_ + 8192 + stoff); \
    gload16(Bp0 + (size_t)(T)*32, nb_ + 16384 + stoff); \
    gload16(Bp1 + (size_t)(T)*32, nb_ + 24576 + stoff); \
  }

  // prologue: 3 tiles in flight
  STAGE(0); STAGE(1); STAGE(2);
  asm volatile("s_waitcnt vmcnt(8)" ::: "memory");   // tile 0 landed
  __builtin_amdgcn_s_barrier();

  for (int kt = 0; kt < NT; ++kt){
    if (kt + 3 < NT) STAGE(kt + 3);
    const char* bb = lds + (kt & 3) * 32768;
    short8 af[8], bfr[4];
    #pragma unroll
    for (int m = 0; m < 8; m++) af[m]  = *(const short8*)(bb + aoff[m]);
    #pragma unroll
    for (int n = 0; n < 4; n++) bfr[n] = *(const short8*)(bb + boff[n]);
    __builtin_amdgcn_s_setprio(1);
    #pragma unroll
    for (int m = 0; m < 8; m++)
      #pragma unroll
      for (int n = 0; n < 4; n++)
        acc[m][n] = __builtin_amdgcn_mfma_f32_16x16x32_bf16(af[m], bfr[n], acc[m][n], 0, 0, 0);
    __builtin_amdgcn_s_setprio(0);
    if (kt + 3 < NT)      { asm volatile("s_waitcnt vmcnt(8)" ::: "memory"); }  // tile kt+1 landed
    else if (kt + 2 < NT) { asm volatile("s_waitcnt vmcnt(4)" ::: "memory"); }
    else if (kt + 1 < NT) { asm volatile("s_waitcnt vmcnt(0)" ::: "memory"); }
    if (kt + 1 < NT) __builtin_amdgcn_s_barrier();
  }
#undef STAGE

  // epilogue: out = (1-a)*x + a * la[row] * (acc*scale + b_v[col]) * ra[b][col]
  float a = alphap[0];
  float scale = scalep[0] * (1.0f / ((float)F_ * (float)F_));
  float oma = 1.0f - a;
  int bidx = row0 >> 11;
  const float* rab = ra + bidx * F_;
  #pragma unroll
  for (int m = 0; m < 8; m++){
    int rbase = row0 + wr*128 + m*16 + kgrp * 4;
    float lav[4];
    #pragma unroll
    for (int r = 0; r < 4; r++) lav[r] = la[rbase + r];
    #pragma unroll
    for (int n = 0; n < 4; n++){
      int col = col0 + wc*64 + n*16 + lrow;
      float rav = rab[col];
      float bvv = bv[col];
      #pragma unroll
      for (int r = 0; r < 4; r++){
        int row = rbase + r;
        float v = acc[m][n][r] * scale + bvv;
        size_t idx = (size_t)row * N_ + col;
        Out[idx] = oma * X[idx] + a * lav[r] * v * rav;
      }
    }
  }
}

// ---------- launch ----------
extern "C" void kernel_launch(void* const* d_in, const int* in_sizes, int n_in,
                              void* d_out, int out_size, void* d_ws, size_t ws_size,
                              hipStream_t stream){
  const float* x     = (const float*)d_in[0];
  const float* Wv    = (const float*)d_in[3];
  const float* bv    = (const float*)d_in[4];
  const float* wl    = (const float*)d_in[5];
  const float* bl    = (const float*)d_in[6];
  const float* wrt   = (const float*)d_in[7];
  const float* br    = (const float*)d_in[8];
  const float* alpha = (const float*)d_in[9];
  float* out = (float*)d_out;

  char* ws = (char*)d_ws;
  unsigned short* XH = (unsigned short*)(ws);              // 67,108,864 B
  unsigned short* BT = (unsigned short*)(ws + 67108864);   //  8,388,608 B
  float* ra_raw = (float*)(ws + 75497472);                 // 65,536 B
  float* scalep = (float*)(ws + 75563008);                 //    256 B (memset with ra_raw)
  float* la_raw = (float*)(ws + 75563264);                 // 65,536 B
  float* la     = (float*)(ws + 75628800);                 // 65,536 B
  float* ra     = (float*)(ws + 75694336);                 // 65,536 B

  hipMemsetAsync(ra_raw, 0, 65536 + 256, stream);          // ra_raw + scalep
  k_abs1<<<4096, 256, 0, stream>>>(Wv, scalep);
  k_quantT<<<dim3(F_/32, F_/32), 256, 0, stream>>>(Wv, BT, scalep);
  k_front<<<M_/32, 256, 0, stream>>>(x, wl, bl, wrt, XH, la_raw, ra_raw);
  k_ln<<<16, 256, 0, stream>>>(la_raw, ra_raw, br, la, ra);
  k_gemm<<<512, 512, 0, stream>>>(XH, BT, x, la, ra, bv, alpha, scalep, out);
}